// Round 3
// baseline (4118.639 us; speedup 1.0000x reference)
//
#include <hip/hip_runtime.h>
#include <hip/hip_bf16.h>

#define DEV __device__ __forceinline__

constexpr int B_ = 256;   // batch
constexpr int T_ = 512;   // time
constexpr int H_ = 128;   // GRU units
constexpr int K_ = 256;   // input dim per layer (D = 2H = 256 for all layers)
constexpr int G_ = 384;   // 3H
constexpr int M_ = B_ * T_;

using bf16 = __hip_bfloat16;
typedef short bf16x8 __attribute__((ext_vector_type(8)));
typedef float f32x4 __attribute__((ext_vector_type(4)));

DEV float tof(float x) { return x; }
DEV float tof(bf16 x) { return __bfloat162float(x); }
DEV void stor(float* p, float v) { *p = v; }
DEV void stor(bf16* p, float v) { *p = __float2bfloat16(v); }

// float -> bf16 bits, round-to-nearest-even
DEV short f2bs(float f) {
  union { float f; unsigned u; } v;
  v.f = f;
  unsigned r = (v.u + 0x7FFFu + ((v.u >> 16) & 1u)) >> 16;
  return (short)r;
}
DEV float bs2f(short s) {
  union { unsigned u; float f; } v;
  v.u = ((unsigned)(unsigned short)s) << 16;
  return v.f;
}

DEV float4 load4(const float* p) { return *(const float4*)p; }
DEV float4 load4(const bf16* p) {
  ushort4 u = *(const ushort4*)(const void*)p;
  union { unsigned int i; float f; } c;
  float4 f;
  c.i = ((unsigned)u.x) << 16; f.x = c.f;
  c.i = ((unsigned)u.y) << 16; f.y = c.f;
  c.i = ((unsigned)u.z) << 16; f.z = c.f;
  c.i = ((unsigned)u.w) << 16; f.w = c.f;
  return f;
}

DEV float fsigmoid(float x) { return 1.f / (1.f + __expf(-x)); }
DEV float ftanh(float x) {
  x = fminf(20.f, fmaxf(-20.f, x));
  float e = __expf(-2.f * x);
  return (1.f - e) / (1.f + e);
}

// Barrier draining only LDS traffic (lgkmcnt), not global loads/stores.
DEV void barrier_lds() {
  asm volatile("s_waitcnt lgkmcnt(0)\n\ts_barrier" ::: "memory");
}

DEV f32x4 mfma16(bf16x8 a, bf16x8 b, f32x4 c) {
  return __builtin_amdgcn_mfma_f32_16x16x32_bf16(a, b, c, 0, 0, 0);
}

// ---------------------------------------------------------------------------
// Input projection GEMM: xp[dir][t][b][0:384] = A[b*T+t][:] @ W[dir] + b_i[dir]
// A: [M, 256] row-major (m = b*T + t). 128x128 tile, 8x8/thread, BK=16. fp32.
// ---------------------------------------------------------------------------
template <typename AT, typename XT>
__global__ __launch_bounds__(256, 2) void inproj_kernel(
    const AT* __restrict__ A, const float* __restrict__ Wbase,
    const float* __restrict__ bbase, XT* __restrict__ xp) {
  const int dir = blockIdx.z;
  const float* W = Wbase + dir * (K_ * G_);
  const float* bi = bbase + dir * (2 * G_);
  const int m0 = blockIdx.x * 128;
  const int n0 = blockIdx.y * 128;
  const int tid = threadIdx.x;
  const int tm = tid >> 4, tn = tid & 15;

  __shared__ __align__(16) float As[16][132];  // [k][m], padded
  __shared__ __align__(16) float Bs[16][132];  // [k][n], padded

  float acc[8][8] = {};

  const int arow = tid >> 1;        // 0..127
  const int ak = (tid & 1) * 8;     // 0 or 8
  const int bk = tid >> 4;          // 0..15
  const int bn = (tid & 15) * 4;    // 0..60

  for (int k0 = 0; k0 < K_; k0 += 16) {
    float4 a0 = load4(A + (m0 + arow) * K_ + k0 + ak);
    float4 a1 = load4(A + (m0 + arow) * K_ + k0 + ak + 4);
    float4 w0 = *(const float4*)(W + (k0 + bk) * G_ + n0 + bn);
    float4 w1 = *(const float4*)(W + (k0 + bk) * G_ + n0 + bn + 64);
    __syncthreads();
    As[ak + 0][arow] = a0.x; As[ak + 1][arow] = a0.y;
    As[ak + 2][arow] = a0.z; As[ak + 3][arow] = a0.w;
    As[ak + 4][arow] = a1.x; As[ak + 5][arow] = a1.y;
    As[ak + 6][arow] = a1.z; As[ak + 7][arow] = a1.w;
    *(float4*)&Bs[bk][bn] = w0;
    *(float4*)&Bs[bk][bn + 64] = w1;
    __syncthreads();
#pragma unroll
    for (int k = 0; k < 16; ++k) {
      float4 x0 = *(const float4*)&As[k][tm * 8];
      float4 x1 = *(const float4*)&As[k][tm * 8 + 4];
      float4 y0 = *(const float4*)&Bs[k][tn * 8];
      float4 y1 = *(const float4*)&Bs[k][tn * 8 + 4];
      float av[8] = {x0.x, x0.y, x0.z, x0.w, x1.x, x1.y, x1.z, x1.w};
      float bv[8] = {y0.x, y0.y, y0.z, y0.w, y1.x, y1.y, y1.z, y1.w};
#pragma unroll
      for (int i = 0; i < 8; ++i)
#pragma unroll
        for (int j = 0; j < 8; ++j) acc[i][j] = fmaf(av[i], bv[j], acc[i][j]);
    }
  }

  float bias[8];
#pragma unroll
  for (int j = 0; j < 8; ++j) bias[j] = bi[n0 + tn * 8 + j];
#pragma unroll
  for (int i = 0; i < 8; ++i) {
    const int m = m0 + tm * 8 + i;
    const int bb = m >> 9;          // T_ = 512
    const int t = m & (T_ - 1);
    XT* dst = xp + ((dir * T_ + t) * B_ + bb) * G_ + n0 + tn * 8;
#pragma unroll
    for (int j = 0; j < 8; ++j) stor(dst + j, acc[i][j] + bias[j]);
  }
}

// ---------------------------------------------------------------------------
// MFMA recurrence. Grid (B/16, 2): 16 batch rows per block, blockIdx.y = dir.
// 512 threads = 8 waves. Wave w owns N-tiles {w, 8+w, 16+w} of h@U, i.e. the
// z,r,h gate columns for units [16w, 16w+16) -> gate math is fully in-register
// (C/D layout: m = quad*4+reg, u = 16w + (lane&15)). h state: fp32 in VGPRs;
// staged per step into LDS as bf16 hi+lo (split) for the A operand.
// U is held in VGPRs as bf16 hi+lo B-fragments (loaded once).
// 3-term split MFMA (hi*hi + hi*lo + lo*hi) ~= fp32 precision.
// Double-buffered h staging -> single lgkm-only barrier per step.
// ---------------------------------------------------------------------------
template <typename XT, typename ST, bool LAST>
__global__ __launch_bounds__(512, 2) void rec_mfma_kernel(
    const XT* __restrict__ xp, const float* __restrict__ Ubase,
    const float* __restrict__ bbase, ST* __restrict__ outSeq,
    float* __restrict__ fin) {
  const int dir = blockIdx.y;
  const float* U = Ubase + dir * (H_ * G_);
  const float* bh = bbase + dir * (2 * G_) + G_;
  const int b0 = blockIdx.x * 16;
  const int tid = threadIdx.x;
  const int w = tid >> 6;
  const int lane = tid & 63;
  const int col = lane & 15;
  const int quad = lane >> 4;

  // h staging: bf16 hi/lo, double buffered. Row stride 136 (16B aligned, +8 pad).
  __shared__ __align__(16) short hbH[2][16 * 136];
  __shared__ __align__(16) short hbL[2][16 * 136];

  // B fragments (U columns for this wave's tiles), hi/lo split, in VGPRs.
  bf16x8 Bhi[3][4], Blo[3][4];
  const int tiles0 = w, tiles1 = 8 + w, tiles2 = 16 + w;
  const int tn_[3] = {tiles0 * 16 + col, tiles1 * 16 + col, tiles2 * 16 + col};
#pragma unroll
  for (int t3 = 0; t3 < 3; ++t3) {
    const int n = tn_[t3];
#pragma unroll
    for (int kb = 0; kb < 4; ++kb) {
#pragma unroll
      for (int jj = 0; jj < 8; ++jj) {
        const int k = kb * 32 + quad * 8 + jj;
        const float f = U[k * G_ + n];
        const short hi = f2bs(f);
        Bhi[t3][kb][jj] = hi;
        Blo[t3][kb][jj] = f2bs(f - bs2f(hi));
      }
    }
  }
  const int u = w * 16 + col;
  const float bhz = bh[u], bhr = bh[H_ + u], bhh = bh[2 * H_ + u];

  // zero staging buffer 0 (h0 = 0)
  for (int i = tid; i < 16 * 136; i += 512) { hbH[0][i] = 0; hbL[0][i] = 0; }

  float hst[4] = {0.f, 0.f, 0.f, 0.f};

  const XT* xb = xp + (size_t)(dir * T_) * B_ * G_;

  // prefetch xp for step 0 (gate rows m = quad*4 + r)
  XT pz[4], pr[4], ph[4];
  {
    const int t0 = dir ? (T_ - 1) : 0;
#pragma unroll
    for (int r = 0; r < 4; ++r) {
      const XT* row = xb + ((size_t)t0 * B_ + b0 + quad * 4 + r) * G_;
      pz[r] = row[u]; pr[r] = row[H_ + u]; ph[r] = row[2 * H_ + u];
    }
  }
  barrier_lds();

  const int aoff = col * 136 + quad * 8;  // A-frag: m = lane&15, k = quad*8+j

  for (int it = 0; it < T_; ++it) {
    const int t = dir ? (T_ - 1 - it) : it;
    const int cur = it & 1, nxt = cur ^ 1;

    // prefetch xp for step it+1 (latency hides under MFMA phase)
    XT qz[4], qr[4], qh[4];
#pragma unroll
    for (int r = 0; r < 4; ++r) { qz[r] = pz[r]; qr[r] = pr[r]; qh[r] = ph[r]; }
    if (it + 1 < T_) {
      const int tnx = dir ? (t - 1) : (t + 1);
#pragma unroll
      for (int r = 0; r < 4; ++r) {
        const XT* row = xb + ((size_t)tnx * B_ + b0 + quad * 4 + r) * G_;
        qz[r] = row[u]; qr[r] = row[H_ + u]; qh[r] = row[2 * H_ + u];
      }
    }

    // A fragments from LDS
    bf16x8 ahi[4], alo[4];
#pragma unroll
    for (int kb = 0; kb < 4; ++kb) {
      ahi[kb] = *(const bf16x8*)&hbH[cur][aoff + kb * 32];
      alo[kb] = *(const bf16x8*)&hbL[cur][aoff + kb * 32];
    }

    // MFMA: a1 = hi*hi chain, a2 = lo*hi + hi*lo chain (independent chains)
    f32x4 a1[3], a2[3];
#pragma unroll
    for (int t3 = 0; t3 < 3; ++t3) { a1[t3] = (f32x4){0.f, 0.f, 0.f, 0.f}; a2[t3] = (f32x4){0.f, 0.f, 0.f, 0.f}; }
#pragma unroll
    for (int kb = 0; kb < 4; ++kb) {
      a1[0] = mfma16(ahi[kb], Bhi[0][kb], a1[0]);
      a1[1] = mfma16(ahi[kb], Bhi[1][kb], a1[1]);
      a1[2] = mfma16(ahi[kb], Bhi[2][kb], a1[2]);
      a2[0] = mfma16(alo[kb], Bhi[0][kb], a2[0]);
      a2[1] = mfma16(alo[kb], Bhi[1][kb], a2[1]);
      a2[2] = mfma16(alo[kb], Bhi[2][kb], a2[2]);
      a2[0] = mfma16(ahi[kb], Blo[0][kb], a2[0]);
      a2[1] = mfma16(ahi[kb], Blo[1][kb], a2[1]);
      a2[2] = mfma16(ahi[kb], Blo[2][kb], a2[2]);
    }

    // gate phase, fully in-register (C/D layout m = quad*4 + r)
#pragma unroll
    for (int r = 0; r < 4; ++r) {
      const int m = quad * 4 + r;
      const float rz = a1[0][r] + a2[0][r] + bhz;
      const float rr = a1[1][r] + a2[1][r] + bhr;
      const float rh = a1[2][r] + a2[2][r] + bhh;
      const float z = fsigmoid(tof(pz[r]) + rz);
      const float rg = fsigmoid(tof(pr[r]) + rr);
      const float hh = ftanh(tof(ph[r]) + rg * rh);
      const float hn = z * hst[r] + (1.f - z) * hh;
      hst[r] = hn;
      const short hi = f2bs(hn);
      hbH[nxt][m * 136 + u] = hi;
      hbL[nxt][m * 136 + u] = f2bs(hn - bs2f(hi));
      if constexpr (!LAST) {
        stor(outSeq + ((size_t)(b0 + m) * T_ + t) * (2 * H_) + dir * H_ + u, hn);
      }
    }
#pragma unroll
    for (int r = 0; r < 4; ++r) { pz[r] = qz[r]; pr[r] = qr[r]; ph[r] = qh[r]; }
    barrier_lds();
  }

  if constexpr (LAST) {
#pragma unroll
    for (int r = 0; r < 4; ++r)
      fin[(size_t)(b0 + quad * 4 + r) * (2 * H_) + dir * H_ + u] = hst[r];
  }
}

// ---------------------------------------------------------------------------
// Dense head: out[b] = sigmoid(fin[b][:] . Wd + bd)
// ---------------------------------------------------------------------------
__global__ void dense_kernel(const float* __restrict__ fin,
                             const float* __restrict__ Wd,
                             const float* __restrict__ bd,
                             float* __restrict__ out) {
  __shared__ float w[2 * H_];
  const int tid = threadIdx.x;
  w[tid] = Wd[tid];
  __syncthreads();
  float s = bd[0];
  const float* row = fin + tid * (2 * H_);
#pragma unroll 8
  for (int jj = 0; jj < 2 * H_; ++jj) s = fmaf(row[jj], w[jj], s);
  out[tid] = 1.f / (1.f + __expf(-s));
}

// ---------------------------------------------------------------------------
template <typename XT, typename ST>
static void run_model(const float* x, const float* Ws, const float* Us,
                      const float* bs, const float* Wd, const float* bd,
                      float* out, char* ws, hipStream_t stream) {
  XT* xp = (XT*)ws;
  const size_t xpB = (size_t)2 * T_ * B_ * G_ * sizeof(XT);
  const size_t seqBy = (size_t)B_ * T_ * 2 * H_ * sizeof(ST);
  ST* sA = (ST*)(ws + xpB);
  ST* sB = (ST*)(ws + xpB + seqBy);
  float* fin = (float*)(ws + xpB + 2 * seqBy);

  const dim3 gG(M_ / 128, G_ / 128, 2);
  ST* sin = nullptr;
  ST* sout = sA;
  for (int l = 0; l < 3; ++l) {
    const float* Wl = Ws + (size_t)l * 2 * K_ * G_;
    const float* bl = bs + (size_t)l * 2 * 2 * G_;
    const float* Ul = Us + (size_t)l * 2 * H_ * G_;
    if (l == 0)
      inproj_kernel<float, XT><<<gG, 256, 0, stream>>>(x, Wl, bl, xp);
    else
      inproj_kernel<ST, XT><<<gG, 256, 0, stream>>>(sin, Wl, bl, xp);
    if (l < 2)
      rec_mfma_kernel<XT, ST, false>
          <<<dim3(B_ / 16, 2), 512, 0, stream>>>(xp, Ul, bl, sout, nullptr);
    else
      rec_mfma_kernel<XT, ST, true>
          <<<dim3(B_ / 16, 2), 512, 0, stream>>>(xp, Ul, bl, (ST*)nullptr, fin);
    sin = sout;
    sout = (sout == sA) ? sB : sA;
  }
  dense_kernel<<<1, B_, 0, stream>>>(fin, Wd, bd, out);
}

extern "C" void kernel_launch(void* const* d_in, const int* in_sizes, int n_in,
                              void* d_out, int out_size, void* d_ws,
                              size_t ws_size, hipStream_t stream) {
  const float* x = (const float*)d_in[0];
  const float* Ws = (const float*)d_in[1];
  const float* Us = (const float*)d_in[2];
  const float* bs = (const float*)d_in[3];
  const float* Wd = (const float*)d_in[4];
  const float* bd = (const float*)d_in[5];
  float* out = (float*)d_out;
  char* ws = (char*)d_ws;

  const size_t finB = (size_t)B_ * 2 * H_ * 4;
  const size_t seq32 = (size_t)B_ * T_ * 2 * H_ * 4;
  const size_t xp32 = (size_t)2 * T_ * B_ * G_ * 4;
  const size_t xp16 = xp32 / 2;
  const size_t tier1 = xp32 + 2 * seq32 + finB;  // ~640 MiB, full fp32
  const size_t tier2 = xp16 + 2 * seq32 + finB;  // bf16 xp
  if (ws_size >= tier1)
    run_model<float, float>(x, Ws, Us, bs, Wd, bd, out, ws, stream);
  else if (ws_size >= tier2)
    run_model<bf16, float>(x, Ws, Us, bs, Wd, bd, out, ws, stream);
  else
    run_model<bf16, bf16>(x, Ws, Us, bs, Wd, bd, out, ws, stream);
}

// Round 4
// 2653.967 us; speedup vs baseline: 1.5519x; 1.5519x over previous
//
#include <hip/hip_runtime.h>
#include <hip/hip_bf16.h>

#define DEV __device__ __forceinline__

constexpr int B_ = 256;   // batch
constexpr int T_ = 512;   // time
constexpr int H_ = 128;   // GRU units
constexpr int K_ = 256;   // input dim per layer (D = 2H = 256 for all layers)
constexpr int G_ = 384;   // 3H
constexpr int M_ = B_ * T_;
constexpr int LDSROW = 72;  // ushorts per LDS tile row (64 data + 8 pad)

using bf16 = __hip_bfloat16;
typedef short bf16x8 __attribute__((ext_vector_type(8)));
typedef float f32x4 __attribute__((ext_vector_type(4)));

DEV float tof(float x) { return x; }
DEV float tof(bf16 x) { return __bfloat162float(x); }
DEV void stor(float* p, float v) { *p = v; }
DEV void stor(bf16* p, float v) { *p = __float2bfloat16(v); }

// float -> bf16 bits, round-to-nearest-even
DEV unsigned short f2bs(float f) {
  union { float f; unsigned u; } v;
  v.f = f;
  unsigned r = (v.u + 0x7FFFu + ((v.u >> 16) & 1u)) >> 16;
  return (unsigned short)r;
}
DEV float bs2f(unsigned short s) {
  union { unsigned u; float f; } v;
  v.u = ((unsigned)s) << 16;
  return v.f;
}

DEV float fsigmoid(float x) { return 1.f / (1.f + __expf(-x)); }
DEV float ftanh(float x) {
  x = fminf(20.f, fmaxf(-20.f, x));
  float e = __expf(-2.f * x);
  return (1.f - e) / (1.f + e);
}

// Barrier draining only LDS traffic (lgkmcnt), not global loads/stores.
DEV void barrier_lds() {
  asm volatile("s_waitcnt lgkmcnt(0)\n\ts_barrier" ::: "memory");
}

DEV f32x4 mfma16(bf16x8 a, bf16x8 b, f32x4 c) {
  return __builtin_amdgcn_mfma_f32_16x16x32_bf16(a, b, c, 0, 0, 0);
}

// ---------------------------------------------------------------------------
// convX: split fp32 x[M,256] into bf16 hi/lo arrays (layer-0 GEMM input).
// ---------------------------------------------------------------------------
__global__ __launch_bounds__(256) void convX_kernel(
    const float* __restrict__ x, ushort* __restrict__ hiA,
    ushort* __restrict__ loA) {
  const int n4 = M_ * K_ / 4;
  for (int idx = blockIdx.x * blockDim.x + threadIdx.x; idx < n4;
       idx += gridDim.x * blockDim.x) {
    float4 v = ((const float4*)x)[idx];
    ushort4 h, l;
    h.x = f2bs(v.x); l.x = f2bs(v.x - bs2f(h.x));
    h.y = f2bs(v.y); l.y = f2bs(v.y - bs2f(h.y));
    h.z = f2bs(v.z); l.z = f2bs(v.z - bs2f(h.z));
    h.w = f2bs(v.w); l.w = f2bs(v.w - bs2f(h.w));
    ((ushort4*)hiA)[idx] = h;
    ((ushort4*)loA)[idx] = l;
  }
}

// ---------------------------------------------------------------------------
// convW: W[dir][256][384] fp32 -> W^T hi/lo bf16 [768 ncol][256 k],
// ncol = dir*384 + j (both dirs merged into one N=768 GEMM).
// ---------------------------------------------------------------------------
__global__ __launch_bounds__(256) void convW_kernel(
    const float* __restrict__ W, ushort* __restrict__ WhiT,
    ushort* __restrict__ WloT) {
  const int ncol = blockIdx.x;           // 0..767
  const int dir = ncol / G_, j = ncol % G_;
  const int k = threadIdx.x;             // 0..255
  const float f = W[((size_t)dir * K_ + k) * G_ + j];
  const unsigned short hi = f2bs(f);
  WhiT[(size_t)ncol * K_ + k] = hi;
  WloT[(size_t)ncol * K_ + k] = f2bs(f - bs2f(hi));
}

// ---------------------------------------------------------------------------
// gemm3: C[M,768] = A[M,256] @ W^T' + bias, bf16 hi/lo 3-term split MFMA.
// 128x128 tile, BK=64, 4 waves (2x2), each wave 4x4 frags of 16x16x32.
// Writes xp[dir][t][b][g] (m = b*T+t, ncol -> dir,g).
// ---------------------------------------------------------------------------
template <typename XT>
__global__ __launch_bounds__(256, 2) void gemm3_kernel(
    const ushort* __restrict__ Ahi, const ushort* __restrict__ Alo,
    const ushort* __restrict__ WhiT, const ushort* __restrict__ WloT,
    const float* __restrict__ bbias,  // layer bias base (bs + l*4*G_)
    XT* __restrict__ xp) {
  const int m0 = blockIdx.x * 128;
  const int n0 = blockIdx.y * 128;
  const int tid = threadIdx.x;
  const int w = tid >> 6, lane = tid & 63;
  const int wm = w >> 1, wn = w & 1;
  const int col = lane & 15, quad = lane >> 4;

  __shared__ __align__(16) ushort AH[128 * LDSROW];
  __shared__ __align__(16) ushort AL[128 * LDSROW];
  __shared__ __align__(16) ushort BH[128 * LDSROW];
  __shared__ __align__(16) ushort BL[128 * LDSROW];

  f32x4 acc[4][4];
#pragma unroll
  for (int i = 0; i < 4; ++i)
#pragma unroll
    for (int n = 0; n < 4; ++n) acc[i][n] = (f32x4){0.f, 0.f, 0.f, 0.f};

  // staging role: wave w stages tile w
  const ushort* gsrc = (w == 0) ? Ahi : (w == 1) ? Alo : (w == 2) ? WhiT : WloT;
  ushort* lds = (w == 0) ? AH : (w == 1) ? AL : (w == 2) ? BH : BL;
  const int rbase = (w < 2) ? m0 : n0;

  for (int kb = 0; kb < K_; kb += 64) {
    // stage 16KB per wave: slot = q*64 + lane; row = slot>>3, chunk = slot&7
#pragma unroll
    for (int q = 0; q < 16; ++q) {
      const int slot = q * 64 + lane;
      const int r = slot >> 3, s = slot & 7;
      bf16x8 v = *(const bf16x8*)(gsrc + (size_t)(rbase + r) * K_ + kb + s * 8);
      *(bf16x8*)&lds[r * LDSROW + s * 8] = v;
    }
    __syncthreads();
#pragma unroll
    for (int z = 0; z < 2; ++z) {
      const int cc8 = (z * 4 + quad) * 8;
      bf16x8 ah[4], al[4], bh[4], bl[4];
#pragma unroll
      for (int i = 0; i < 4; ++i) {
        const int row = wm * 64 + i * 16 + col;
        ah[i] = *(const bf16x8*)&AH[row * LDSROW + cc8];
        al[i] = *(const bf16x8*)&AL[row * LDSROW + cc8];
      }
#pragma unroll
      for (int n = 0; n < 4; ++n) {
        const int row = wn * 64 + n * 16 + col;
        bh[n] = *(const bf16x8*)&BH[row * LDSROW + cc8];
        bl[n] = *(const bf16x8*)&BL[row * LDSROW + cc8];
      }
#pragma unroll
      for (int i = 0; i < 4; ++i)
#pragma unroll
        for (int n = 0; n < 4; ++n) {
          acc[i][n] = mfma16(ah[i], bh[n], acc[i][n]);
          acc[i][n] = mfma16(al[i], bh[n], acc[i][n]);
          acc[i][n] = mfma16(ah[i], bl[n], acc[i][n]);
        }
    }
    __syncthreads();
  }

  // epilogue: C/D layout m = quad*4 + r, n = col
  const int dir = (n0 >= G_) ? 1 : 0;
#pragma unroll
  for (int n = 0; n < 4; ++n) {
    const int ncol = n0 + wn * 64 + n * 16 + col;
    const int g = ncol - dir * G_;
    const float bv = bbias[dir * 2 * G_ + g];
#pragma unroll
    for (int i = 0; i < 4; ++i) {
      const int mb = m0 + wm * 64 + i * 16 + quad * 4;
#pragma unroll
      for (int r = 0; r < 4; ++r) {
        const int m = mb + r;
        const int bb = m >> 9;          // T_ = 512
        const int t = m & (T_ - 1);
        stor(xp + ((size_t)(dir * T_ + t) * B_ + bb) * G_ + g,
             acc[i][n][r] + bv);
      }
    }
  }
}

// ---------------------------------------------------------------------------
// Recurrence (R2-proven). Grid (128, 2): blockIdx.y = dir, 2 batch rows/block.
// 768 threads. Column j = (tid&31)|((tid>>6)<<5); half = (tid>>5)&1 holds
// U[half*64 + 0..63, j] in VGPRs. Bank-conflict-free hbuf broadcast reads.
// xp for step t+1 prefetched during step t's dot phase.
// Sequence output stored as bf16 hi/lo pair (next layer's GEMM A operand).
// ---------------------------------------------------------------------------
template <typename XT, bool LAST>
__global__ __launch_bounds__(768, 3) void rec_kernel(
    const XT* __restrict__ xp, const float* __restrict__ Ubase,
    const float* __restrict__ bbase, ushort* __restrict__ seqH,
    ushort* __restrict__ seqL, float* __restrict__ fin) {
  const int dir = blockIdx.y;
  const float* U = Ubase + dir * (H_ * G_);
  const float* bh = bbase + dir * (2 * G_) + G_;
  const int b0 = blockIdx.x * 2;
  const int tid = threadIdx.x;
  const int half = (tid >> 5) & 1;                 // wave lanes 0-31 vs 32-63
  const int j = (tid & 31) | ((tid >> 6) << 5);    // 0..383

  __shared__ __align__(16) float hbuf[2][H_];
  __shared__ float rec_s[2][G_];

  float Ureg[64];
#pragma unroll
  for (int kk = 0; kk < 64; ++kk) Ureg[kk] = U[(half * 64 + kk) * G_ + j];
  const float bhj = bh[j];

  const int grow = tid >> 7;        // gate-phase row (tid < 256)
  const int gu = tid & (H_ - 1);    // gate-phase unit
  const bool gateT = tid < 2 * H_;

  if (gateT) hbuf[grow][gu] = 0.f;

  const XT* xbase = xp + (size_t)(dir * T_) * B_ * G_;

  // prefetch step 0 (raw XT regs; conversion deferred to use site)
  XT xzc{}, xrc{}, xhc{};
  {
    const int t0 = dir ? (T_ - 1) : 0;
    if (gateT) {
      const XT* xr_ = xbase + ((size_t)t0 * B_ + b0 + grow) * G_ + gu;
      xzc = xr_[0];
      xrc = xr_[H_];
      xhc = xr_[2 * H_];
    }
  }
  barrier_lds();

  for (int it = 0; it < T_; ++it) {
    const int t = dir ? (T_ - 1 - it) : it;

    // --- prefetch xp for step it+1 (hidden under the dot phase) ---
    XT xzn = xzc, xrn = xrc, xhn = xhc;
    if (gateT && (it + 1 < T_)) {
      const int tn = dir ? (t - 1) : (t + 1);
      const XT* xr_ = xbase + ((size_t)tn * B_ + b0 + grow) * G_ + gu;
      xzn = xr_[0];
      xrn = xr_[H_];
      xhn = xr_[2 * H_];
    }

    // --- dot phase: rec[row][j] = sum_k h[row][k] * U[k][j] ---
    float a0[4] = {0.f, 0.f, 0.f, 0.f};
    float a1[4] = {0.f, 0.f, 0.f, 0.f};
#pragma unroll
    for (int q = 0; q < 16; ++q) {
      float4 h0 = *(const float4*)&hbuf[0][half * 64 + q * 4];
      float4 h1 = *(const float4*)&hbuf[1][half * 64 + q * 4];
      const int c = q & 3;
      a0[c] = fmaf(h0.x, Ureg[q * 4 + 0], a0[c]);
      a0[c] = fmaf(h0.y, Ureg[q * 4 + 1], a0[c]);
      a0[c] = fmaf(h0.z, Ureg[q * 4 + 2], a0[c]);
      a0[c] = fmaf(h0.w, Ureg[q * 4 + 3], a0[c]);
      a1[c] = fmaf(h1.x, Ureg[q * 4 + 0], a1[c]);
      a1[c] = fmaf(h1.y, Ureg[q * 4 + 1], a1[c]);
      a1[c] = fmaf(h1.z, Ureg[q * 4 + 2], a1[c]);
      a1[c] = fmaf(h1.w, Ureg[q * 4 + 3], a1[c]);
    }
    float r0 = (a0[0] + a0[1]) + (a0[2] + a0[3]);
    float r1 = (a1[0] + a1[1]) + (a1[2] + a1[3]);
    r0 += __shfl_xor(r0, 32);
    r1 += __shfl_xor(r1, 32);
    if (half == 0) {
      rec_s[0][j] = r0 + bhj;
      rec_s[1][j] = r1 + bhj;
    }
    barrier_lds();

    // --- gate phase (first 256 threads) ---
    if (gateT) {
      const float xz = tof(xzc);
      const float xr = tof(xrc);
      const float xh = tof(xhc);
      const float rz = rec_s[grow][gu];
      const float rr = rec_s[grow][H_ + gu];
      const float rh = rec_s[grow][2 * H_ + gu];
      const float z = fsigmoid(xz + rz);
      const float r = fsigmoid(xr + rr);
      const float hh = ftanh(xh + r * rh);
      const float hold = hbuf[grow][gu];
      const float hn = z * hold + (1.f - z) * hh;
      hbuf[grow][gu] = hn;
      if constexpr (!LAST) {
        const size_t sidx =
            ((size_t)(b0 + grow) * T_ + t) * (2 * H_) + dir * H_ + gu;
        const unsigned short hi = f2bs(hn);
        seqH[sidx] = hi;
        seqL[sidx] = f2bs(hn - bs2f(hi));
      }
      xzc = xzn;
      xrc = xrn;
      xhc = xhn;
    }
    barrier_lds();
  }

  if constexpr (LAST) {
    if (gateT) fin[(size_t)(b0 + grow) * (2 * H_) + dir * H_ + gu] =
        hbuf[grow][gu];
  }
}

// ---------------------------------------------------------------------------
// Dense head: out[b] = sigmoid(fin[b][:] . Wd + bd)
// ---------------------------------------------------------------------------
__global__ void dense_kernel(const float* __restrict__ fin,
                             const float* __restrict__ Wd,
                             const float* __restrict__ bd,
                             float* __restrict__ out) {
  __shared__ float w[2 * H_];
  const int tid = threadIdx.x;
  w[tid] = Wd[tid];
  __syncthreads();
  float s = bd[0];
  const float* row = fin + tid * (2 * H_);
#pragma unroll 8
  for (int jj = 0; jj < 2 * H_; ++jj) s = fmaf(row[jj], w[jj], s);
  out[tid] = 1.f / (1.f + __expf(-s));
}

// ---------------------------------------------------------------------------
template <typename XT>
static void run_model(const float* x, const float* Ws, const float* Us,
                      const float* bs, const float* Wd, const float* bd,
                      float* out, char* ws, hipStream_t stream) {
  const size_t xpB = (size_t)2 * T_ * B_ * G_ * sizeof(XT);
  const size_t seqB = (size_t)B_ * T_ * 2 * H_ * 2;  // bf16 bits
  XT* xp = (XT*)ws;
  ushort* sHA = (ushort*)(ws + xpB);
  ushort* sLA = (ushort*)(ws + xpB + seqB);
  ushort* sHB = (ushort*)(ws + xpB + 2 * seqB);
  ushort* sLB = (ushort*)(ws + xpB + 3 * seqB);
  ushort* WhiT = (ushort*)(ws + xpB + 4 * seqB);
  ushort* WloT = WhiT + (size_t)768 * K_;
  float* fin = (float*)(ws + xpB + 4 * seqB + (size_t)2 * 768 * K_ * 2);

  // layer-0 A operand: split x into the "B" ping-pong slot
  convX_kernel<<<4096, 256, 0, stream>>>(x, sHB, sLB);

  const ushort* AHs[3] = {sHB, sHA, sHB};
  const ushort* ALs[3] = {sLB, sLA, sLB};
  ushort* oH[3] = {sHA, sHB, nullptr};
  ushort* oL[3] = {sLA, sLB, nullptr};

  for (int l = 0; l < 3; ++l) {
    const float* Wl = Ws + (size_t)l * 2 * K_ * G_;
    const float* bl = bs + (size_t)l * 4 * G_;
    const float* Ul = Us + (size_t)l * 2 * H_ * G_;
    convW_kernel<<<768, 256, 0, stream>>>(Wl, WhiT, WloT);
    gemm3_kernel<XT><<<dim3(M_ / 128, 6), 256, 0, stream>>>(
        AHs[l], ALs[l], WhiT, WloT, bl, xp);
    if (l < 2)
      rec_kernel<XT, false><<<dim3(B_ / 2, 2), 768, 0, stream>>>(
          xp, Ul, bl, oH[l], oL[l], nullptr);
    else
      rec_kernel<XT, true><<<dim3(B_ / 2, 2), 768, 0, stream>>>(
          xp, Ul, bl, nullptr, nullptr, fin);
  }
  dense_kernel<<<1, B_, 0, stream>>>(fin, Wd, bd, out);
}

extern "C" void kernel_launch(void* const* d_in, const int* in_sizes, int n_in,
                              void* d_out, int out_size, void* d_ws,
                              size_t ws_size, hipStream_t stream) {
  const float* x = (const float*)d_in[0];
  const float* Ws = (const float*)d_in[1];
  const float* Us = (const float*)d_in[2];
  const float* bs = (const float*)d_in[3];
  const float* Wd = (const float*)d_in[4];
  const float* bd = (const float*)d_in[5];
  float* out = (float*)d_out;
  char* ws = (char*)d_ws;

  const size_t seqB = (size_t)B_ * T_ * 2 * H_ * 2;
  const size_t wtB = (size_t)2 * 768 * K_ * 2;
  const size_t finB = (size_t)B_ * 2 * H_ * 4;
  const size_t xp32 = (size_t)2 * T_ * B_ * G_ * 4;
  const size_t tierA = xp32 + 4 * seqB + wtB + finB;      // ~641 MiB, fp32 xp
  if (ws_size >= tierA)
    run_model<float>(x, Ws, Us, bs, Wd, bd, out, ws, stream);
  else
    run_model<bf16>(x, Ws, Us, bs, Wd, bd, out, ws, stream);
}

// Round 5
// 2586.131 us; speedup vs baseline: 1.5926x; 1.0262x over previous
//
#include <hip/hip_runtime.h>
#include <hip/hip_bf16.h>

#define DEV __device__ __forceinline__

constexpr int B_ = 256;   // batch
constexpr int T_ = 512;   // time
constexpr int H_ = 128;   // GRU units
constexpr int K_ = 256;   // input dim per layer (D = 2H = 256 for all layers)
constexpr int G_ = 384;   // 3H
constexpr int M_ = B_ * T_;
constexpr int LDSROW = 72;  // ushorts per LDS tile row (64 data + 8 pad)

using bf16 = __hip_bfloat16;
typedef short bf16x8 __attribute__((ext_vector_type(8)));
typedef float f32x4 __attribute__((ext_vector_type(4)));

DEV float tof(float x) { return x; }
DEV float tof(bf16 x) { return __bfloat162float(x); }
DEV void stor(float* p, float v) { *p = v; }
DEV void stor(bf16* p, float v) { *p = __float2bfloat16(v); }

// float -> bf16 bits, round-to-nearest-even
DEV unsigned short f2bs(float f) {
  union { float f; unsigned u; } v;
  v.f = f;
  unsigned r = (v.u + 0x7FFFu + ((v.u >> 16) & 1u)) >> 16;
  return (unsigned short)r;
}
DEV float bs2f(unsigned short s) {
  union { unsigned u; float f; } v;
  v.u = ((unsigned)s) << 16;
  return v.f;
}

DEV float fsigmoid(float x) { return 1.f / (1.f + __expf(-x)); }
DEV float ftanh(float x) {
  x = fminf(20.f, fmaxf(-20.f, x));
  float e = __expf(-2.f * x);
  return (1.f - e) / (1.f + e);
}

// Barrier draining only LDS traffic (lgkmcnt), not global loads/stores.
DEV void barrier_lds() {
  asm volatile("s_waitcnt lgkmcnt(0)\n\ts_barrier" ::: "memory");
}

// Pin a float4 into VGPRs: opaque to the optimizer -> no remat, no re-load.
DEV void pin4(float4& v) {
  asm volatile("" : "+v"(v.x), "+v"(v.y), "+v"(v.z), "+v"(v.w));
}

DEV f32x4 mfma16(bf16x8 a, bf16x8 b, f32x4 c) {
  return __builtin_amdgcn_mfma_f32_16x16x32_bf16(a, b, c, 0, 0, 0);
}

// ---------------------------------------------------------------------------
// convX: split fp32 x[M,256] into bf16 hi/lo arrays (layer-0 GEMM input).
// ---------------------------------------------------------------------------
__global__ __launch_bounds__(256) void convX_kernel(
    const float* __restrict__ x, ushort* __restrict__ hiA,
    ushort* __restrict__ loA) {
  const int n4 = M_ * K_ / 4;
  for (int idx = blockIdx.x * blockDim.x + threadIdx.x; idx < n4;
       idx += gridDim.x * blockDim.x) {
    float4 v = ((const float4*)x)[idx];
    ushort4 h, l;
    h.x = f2bs(v.x); l.x = f2bs(v.x - bs2f(h.x));
    h.y = f2bs(v.y); l.y = f2bs(v.y - bs2f(h.y));
    h.z = f2bs(v.z); l.z = f2bs(v.z - bs2f(h.z));
    h.w = f2bs(v.w); l.w = f2bs(v.w - bs2f(h.w));
    ((ushort4*)hiA)[idx] = h;
    ((ushort4*)loA)[idx] = l;
  }
}

// ---------------------------------------------------------------------------
// convW: W[dir][256][384] fp32 -> W^T hi/lo bf16 [768 ncol][256 k],
// ncol = dir*384 + j (both dirs merged into one N=768 GEMM).
// ---------------------------------------------------------------------------
__global__ __launch_bounds__(256) void convW_kernel(
    const float* __restrict__ W, ushort* __restrict__ WhiT,
    ushort* __restrict__ WloT) {
  const int ncol = blockIdx.x;           // 0..767
  const int dir = ncol / G_, j = ncol % G_;
  const int k = threadIdx.x;             // 0..255
  const float f = W[((size_t)dir * K_ + k) * G_ + j];
  const unsigned short hi = f2bs(f);
  WhiT[(size_t)ncol * K_ + k] = hi;
  WloT[(size_t)ncol * K_ + k] = f2bs(f - bs2f(hi));
}

// ---------------------------------------------------------------------------
// gemm3: C[M,768] = A[M,256] @ W^T' + bias, bf16 hi/lo 3-term split MFMA.
// 128x128 tile, BK=64, 4 waves (2x2), each wave 4x4 frags of 16x16x32.
// Writes xp[dir][t][b][g] (m = b*T+t, ncol -> dir,g).
// ---------------------------------------------------------------------------
template <typename XT>
__global__ __launch_bounds__(256, 2) void gemm3_kernel(
    const ushort* __restrict__ Ahi, const ushort* __restrict__ Alo,
    const ushort* __restrict__ WhiT, const ushort* __restrict__ WloT,
    const float* __restrict__ bbias,  // layer bias base (bs + l*4*G_)
    XT* __restrict__ xp) {
  const int m0 = blockIdx.x * 128;
  const int n0 = blockIdx.y * 128;
  const int tid = threadIdx.x;
  const int w = tid >> 6, lane = tid & 63;
  const int wm = w >> 1, wn = w & 1;
  const int col = lane & 15, quad = lane >> 4;

  __shared__ __align__(16) ushort AH[128 * LDSROW];
  __shared__ __align__(16) ushort AL[128 * LDSROW];
  __shared__ __align__(16) ushort BH[128 * LDSROW];
  __shared__ __align__(16) ushort BL[128 * LDSROW];

  f32x4 acc[4][4];
#pragma unroll
  for (int i = 0; i < 4; ++i)
#pragma unroll
    for (int n = 0; n < 4; ++n) acc[i][n] = (f32x4){0.f, 0.f, 0.f, 0.f};

  // staging role: wave w stages tile w
  const ushort* gsrc = (w == 0) ? Ahi : (w == 1) ? Alo : (w == 2) ? WhiT : WloT;
  ushort* lds = (w == 0) ? AH : (w == 1) ? AL : (w == 2) ? BH : BL;
  const int rbase = (w < 2) ? m0 : n0;

  for (int kb = 0; kb < K_; kb += 64) {
    // stage 16KB per wave: slot = q*64 + lane; row = slot>>3, chunk = slot&7
#pragma unroll
    for (int q = 0; q < 16; ++q) {
      const int slot = q * 64 + lane;
      const int r = slot >> 3, s = slot & 7;
      bf16x8 v = *(const bf16x8*)(gsrc + (size_t)(rbase + r) * K_ + kb + s * 8);
      *(bf16x8*)&lds[r * LDSROW + s * 8] = v;
    }
    __syncthreads();
#pragma unroll
    for (int z = 0; z < 2; ++z) {
      const int cc8 = (z * 4 + quad) * 8;
      bf16x8 ah[4], al[4], bh[4], bl[4];
#pragma unroll
      for (int i = 0; i < 4; ++i) {
        const int row = wm * 64 + i * 16 + col;
        ah[i] = *(const bf16x8*)&AH[row * LDSROW + cc8];
        al[i] = *(const bf16x8*)&AL[row * LDSROW + cc8];
      }
#pragma unroll
      for (int n = 0; n < 4; ++n) {
        const int row = wn * 64 + n * 16 + col;
        bh[n] = *(const bf16x8*)&BH[row * LDSROW + cc8];
        bl[n] = *(const bf16x8*)&BL[row * LDSROW + cc8];
      }
#pragma unroll
      for (int i = 0; i < 4; ++i)
#pragma unroll
        for (int n = 0; n < 4; ++n) {
          acc[i][n] = mfma16(ah[i], bh[n], acc[i][n]);
          acc[i][n] = mfma16(al[i], bh[n], acc[i][n]);
          acc[i][n] = mfma16(ah[i], bl[n], acc[i][n]);
        }
    }
    __syncthreads();
  }

  // epilogue: C/D layout m = quad*4 + r, n = col
  const int dir = (n0 >= G_) ? 1 : 0;
#pragma unroll
  for (int n = 0; n < 4; ++n) {
    const int ncol = n0 + wn * 64 + n * 16 + col;
    const int g = ncol - dir * G_;
    const float bv = bbias[dir * 2 * G_ + g];
#pragma unroll
    for (int i = 0; i < 4; ++i) {
      const int mb = m0 + wm * 64 + i * 16 + quad * 4;
#pragma unroll
      for (int r = 0; r < 4; ++r) {
        const int m = mb + r;
        const int bb = m >> 9;          // T_ = 512
        const int t = m & (T_ - 1);
        stor(xp + ((size_t)(dir * T_ + t) * B_ + bb) * G_ + g,
             acc[i][n][r] + bv);
      }
    }
  }
}

// ---------------------------------------------------------------------------
// Recurrence. Grid (128, 2): blockIdx.y = dir, 2 batch rows/block.
// 768 threads. Column j = (tid&31)|((tid>>6)<<5); half = (tid>>5)&1 holds
// U[half*64 + 0..63, j] PINNED in VGPRs (empty-asm pin stops the compiler
// from rematerializing the loads every step — R4's VGPR_Count=56 showed U
// was being re-fetched from L2 each step, ~37 TB/s = L2-bound).
// Bank-conflict-free hbuf broadcast reads; xp prefetched one step ahead.
// Sequence output stored as bf16 hi/lo pair (next layer's GEMM A operand).
// ---------------------------------------------------------------------------
template <typename XT, bool LAST>
__global__ __launch_bounds__(768, 3) void rec_kernel(
    const XT* __restrict__ xp, const float* __restrict__ Ubase,
    const float* __restrict__ bbase, ushort* __restrict__ seqH,
    ushort* __restrict__ seqL, float* __restrict__ fin) {
  const int dir = blockIdx.y;
  const float* U = Ubase + dir * (H_ * G_);
  const float* bh = bbase + dir * (2 * G_) + G_;
  const int b0 = blockIdx.x * 2;
  const int tid = threadIdx.x;
  const int half = (tid >> 5) & 1;                 // wave lanes 0-31 vs 32-63
  const int j = (tid & 31) | ((tid >> 6) << 5);    // 0..383

  __shared__ __align__(16) float hbuf[2][H_];
  __shared__ float rec_s[2][G_];

  float4 Ureg[16];
#pragma unroll
  for (int q = 0; q < 16; ++q) {
    Ureg[q].x = U[(half * 64 + q * 4 + 0) * G_ + j];
    Ureg[q].y = U[(half * 64 + q * 4 + 1) * G_ + j];
    Ureg[q].z = U[(half * 64 + q * 4 + 2) * G_ + j];
    Ureg[q].w = U[(half * 64 + q * 4 + 3) * G_ + j];
  }
#pragma unroll
  for (int q = 0; q < 16; ++q) pin4(Ureg[q]);
  const float bhj = bh[j];

  const int grow = tid >> 7;        // gate-phase row (tid < 256)
  const int gu = tid & (H_ - 1);    // gate-phase unit
  const bool gateT = tid < 2 * H_;

  if (gateT) hbuf[grow][gu] = 0.f;

  const XT* xbase = xp + (size_t)(dir * T_) * B_ * G_;

  // prefetch step 0 (raw XT regs; conversion deferred to use site)
  XT xzc{}, xrc{}, xhc{};
  {
    const int t0 = dir ? (T_ - 1) : 0;
    if (gateT) {
      const XT* xr_ = xbase + ((size_t)t0 * B_ + b0 + grow) * G_ + gu;
      xzc = xr_[0];
      xrc = xr_[H_];
      xhc = xr_[2 * H_];
    }
  }
  barrier_lds();

  for (int it = 0; it < T_; ++it) {
    const int t = dir ? (T_ - 1 - it) : it;

    // --- prefetch xp for step it+1 (hidden under the dot phase) ---
    XT xzn = xzc, xrn = xrc, xhn = xhc;
    if (gateT && (it + 1 < T_)) {
      const int tn = dir ? (t - 1) : (t + 1);
      const XT* xr_ = xbase + ((size_t)tn * B_ + b0 + grow) * G_ + gu;
      xzn = xr_[0];
      xrn = xr_[H_];
      xhn = xr_[2 * H_];
    }

    // --- dot phase: rec[row][j] = sum_k h[row][k] * U[k][j] ---
    float a0[4] = {0.f, 0.f, 0.f, 0.f};
    float a1[4] = {0.f, 0.f, 0.f, 0.f};
#pragma unroll
    for (int q = 0; q < 16; ++q) {
      float4 h0 = *(const float4*)&hbuf[0][half * 64 + q * 4];
      float4 h1 = *(const float4*)&hbuf[1][half * 64 + q * 4];
      const int c = q & 3;
      a0[c] = fmaf(h0.x, Ureg[q].x, a0[c]);
      a0[c] = fmaf(h0.y, Ureg[q].y, a0[c]);
      a0[c] = fmaf(h0.z, Ureg[q].z, a0[c]);
      a0[c] = fmaf(h0.w, Ureg[q].w, a0[c]);
      a1[c] = fmaf(h1.x, Ureg[q].x, a1[c]);
      a1[c] = fmaf(h1.y, Ureg[q].y, a1[c]);
      a1[c] = fmaf(h1.z, Ureg[q].z, a1[c]);
      a1[c] = fmaf(h1.w, Ureg[q].w, a1[c]);
    }
    float r0 = (a0[0] + a0[1]) + (a0[2] + a0[3]);
    float r1 = (a1[0] + a1[1]) + (a1[2] + a1[3]);
    r0 += __shfl_xor(r0, 32);
    r1 += __shfl_xor(r1, 32);
    if (half == 0) {
      rec_s[0][j] = r0 + bhj;
      rec_s[1][j] = r1 + bhj;
    }
    barrier_lds();

    // --- gate phase (first 256 threads) ---
    if (gateT) {
      const float xz = tof(xzc);
      const float xr = tof(xrc);
      const float xh = tof(xhc);
      const float rz = rec_s[grow][gu];
      const float rr = rec_s[grow][H_ + gu];
      const float rh = rec_s[grow][2 * H_ + gu];
      const float z = fsigmoid(xz + rz);
      const float r = fsigmoid(xr + rr);
      const float hh = ftanh(xh + r * rh);
      const float hold = hbuf[grow][gu];
      const float hn = z * hold + (1.f - z) * hh;
      hbuf[grow][gu] = hn;
      if constexpr (!LAST) {
        const size_t sidx =
            ((size_t)(b0 + grow) * T_ + t) * (2 * H_) + dir * H_ + gu;
        const unsigned short hi = f2bs(hn);
        seqH[sidx] = hi;
        seqL[sidx] = f2bs(hn - bs2f(hi));
      }
      xzc = xzn;
      xrc = xrn;
      xhc = xhn;
    }
    barrier_lds();
  }

  if constexpr (LAST) {
    if (gateT) fin[(size_t)(b0 + grow) * (2 * H_) + dir * H_ + gu] =
        hbuf[grow][gu];
  }
}

// ---------------------------------------------------------------------------
// Dense head: out[b] = sigmoid(fin[b][:] . Wd + bd)
// ---------------------------------------------------------------------------
__global__ void dense_kernel(const float* __restrict__ fin,
                             const float* __restrict__ Wd,
                             const float* __restrict__ bd,
                             float* __restrict__ out) {
  __shared__ float w[2 * H_];
  const int tid = threadIdx.x;
  w[tid] = Wd[tid];
  __syncthreads();
  float s = bd[0];
  const float* row = fin + tid * (2 * H_);
#pragma unroll 8
  for (int jj = 0; jj < 2 * H_; ++jj) s = fmaf(row[jj], w[jj], s);
  out[tid] = 1.f / (1.f + __expf(-s));
}

// ---------------------------------------------------------------------------
template <typename XT>
static void run_model(const float* x, const float* Ws, const float* Us,
                      const float* bs, const float* Wd, const float* bd,
                      float* out, char* ws, hipStream_t stream) {
  const size_t xpB = (size_t)2 * T_ * B_ * G_ * sizeof(XT);
  const size_t seqB = (size_t)B_ * T_ * 2 * H_ * 2;  // bf16 bits
  XT* xp = (XT*)ws;
  ushort* sHA = (ushort*)(ws + xpB);
  ushort* sLA = (ushort*)(ws + xpB + seqB);
  ushort* sHB = (ushort*)(ws + xpB + 2 * seqB);
  ushort* sLB = (ushort*)(ws + xpB + 3 * seqB);
  ushort* WhiT = (ushort*)(ws + xpB + 4 * seqB);
  ushort* WloT = WhiT + (size_t)768 * K_;
  float* fin = (float*)(ws + xpB + 4 * seqB + (size_t)2 * 768 * K_ * 2);

  // layer-0 A operand: split x into the "B" ping-pong slot
  convX_kernel<<<4096, 256, 0, stream>>>(x, sHB, sLB);

  const ushort* AHs[3] = {sHB, sHA, sHB};
  const ushort* ALs[3] = {sLB, sLA, sLB};
  ushort* oH[3] = {sHA, sHB, nullptr};
  ushort* oL[3] = {sLA, sLB, nullptr};

  for (int l = 0; l < 3; ++l) {
    const float* Wl = Ws + (size_t)l * 2 * K_ * G_;
    const float* bl = bs + (size_t)l * 4 * G_;
    const float* Ul = Us + (size_t)l * 2 * H_ * G_;
    convW_kernel<<<768, 256, 0, stream>>>(Wl, WhiT, WloT);
    gemm3_kernel<XT><<<dim3(M_ / 128, 6), 256, 0, stream>>>(
        AHs[l], ALs[l], WhiT, WloT, bl, xp);
    if (l < 2)
      rec_kernel<XT, false><<<dim3(B_ / 2, 2), 768, 0, stream>>>(
          xp, Ul, bl, oH[l], oL[l], nullptr);
    else
      rec_kernel<XT, true><<<dim3(B_ / 2, 2), 768, 0, stream>>>(
          xp, Ul, bl, nullptr, nullptr, fin);
  }
  dense_kernel<<<1, B_, 0, stream>>>(fin, Wd, bd, out);
}

extern "C" void kernel_launch(void* const* d_in, const int* in_sizes, int n_in,
                              void* d_out, int out_size, void* d_ws,
                              size_t ws_size, hipStream_t stream) {
  const float* x = (const float*)d_in[0];
  const float* Ws = (const float*)d_in[1];
  const float* Us = (const float*)d_in[2];
  const float* bs = (const float*)d_in[3];
  const float* Wd = (const float*)d_in[4];
  const float* bd = (const float*)d_in[5];
  float* out = (float*)d_out;
  char* ws = (char*)d_ws;

  const size_t seqB = (size_t)B_ * T_ * 2 * H_ * 2;
  const size_t wtB = (size_t)2 * 768 * K_ * 2;
  const size_t finB = (size_t)B_ * 2 * H_ * 4;
  const size_t xp32 = (size_t)2 * T_ * B_ * G_ * 4;
  const size_t tierA = xp32 + 4 * seqB + wtB + finB;      // ~641 MiB, fp32 xp
  if (ws_size >= tierA)
    run_model<float>(x, Ws, Us, bs, Wd, bd, out, ws, stream);
  else
    run_model<bf16>(x, Ws, Us, bs, Wd, bd, out, ws, stream);
}

// Round 6
// 2233.640 us; speedup vs baseline: 1.8439x; 1.1578x over previous
//
#include <hip/hip_runtime.h>
#include <hip/hip_bf16.h>

#define DEV __device__ __forceinline__

constexpr int B_ = 256;   // batch
constexpr int T_ = 512;   // time
constexpr int H_ = 128;   // GRU units
constexpr int K_ = 256;   // input dim per layer (D = 2H = 256 for all layers)
constexpr int G_ = 384;   // 3H
constexpr int M_ = B_ * T_;
constexpr int LDSROW = 72;  // ushorts per LDS tile row (64 data + 8 pad)

using bf16 = __hip_bfloat16;
typedef short bf16x8 __attribute__((ext_vector_type(8)));
typedef float f32x4 __attribute__((ext_vector_type(4)));
typedef float f32x2 __attribute__((ext_vector_type(2)));

DEV float tof(float x) { return x; }
DEV float tof(bf16 x) { return __bfloat162float(x); }
DEV void stor(float* p, float v) { *p = v; }
DEV void stor(bf16* p, float v) { *p = __float2bfloat16(v); }

// float -> bf16 bits, round-to-nearest-even
DEV unsigned short f2bs(float f) {
  union { float f; unsigned u; } v;
  v.f = f;
  unsigned r = (v.u + 0x7FFFu + ((v.u >> 16) & 1u)) >> 16;
  return (unsigned short)r;
}
DEV float bs2f(unsigned short s) {
  union { unsigned u; float f; } v;
  v.u = ((unsigned)s) << 16;
  return v.f;
}

DEV float fsigmoid(float x) { return 1.f / (1.f + __expf(-x)); }
DEV float ftanh(float x) {
  x = fminf(20.f, fmaxf(-20.f, x));
  float e = __expf(-2.f * x);
  return (1.f - e) / (1.f + e);
}

// Barrier draining only LDS traffic (lgkmcnt), not global loads/stores.
DEV void barrier_lds() {
  asm volatile("s_waitcnt lgkmcnt(0)\n\ts_barrier" ::: "memory");
}

// Pin a float4 into VGPRs (opaque to the optimizer).
DEV void pin4(float4& v) {
  asm volatile("" : "+v"(v.x), "+v"(v.y), "+v"(v.z), "+v"(v.w));
}

DEV f32x4 mfma16(bf16x8 a, bf16x8 b, f32x4 c) {
  return __builtin_amdgcn_mfma_f32_16x16x32_bf16(a, b, c, 0, 0, 0);
}

// Butterfly sum over 8-lane groups, entirely on the VALU pipe (DPP), keeping
// the LDS pipe free. Masks {1,2,7}: quad_perm[1,0,3,2]=0xB1, quad_perm[2,3,0,1]
// =0x4E, row_half_mirror=0x141 (xor7 group-local). Span{1,2,7} = full 8-group.
DEV float dpp_red8(float x) {
  int t;
  t = __builtin_amdgcn_update_dpp(0, __float_as_int(x), 0xB1, 0xF, 0xF, true);
  x += __int_as_float(t);
  t = __builtin_amdgcn_update_dpp(0, __float_as_int(x), 0x4E, 0xF, 0xF, true);
  x += __int_as_float(t);
  t = __builtin_amdgcn_update_dpp(0, __float_as_int(x), 0x141, 0xF, 0xF, true);
  x += __int_as_float(t);
  return x;
}

// ---------------------------------------------------------------------------
// convX: split fp32 x[M,256] into bf16 hi/lo arrays (layer-0 GEMM input).
// ---------------------------------------------------------------------------
__global__ __launch_bounds__(256) void convX_kernel(
    const float* __restrict__ x, ushort* __restrict__ hiA,
    ushort* __restrict__ loA) {
  const int n4 = M_ * K_ / 4;
  for (int idx = blockIdx.x * blockDim.x + threadIdx.x; idx < n4;
       idx += gridDim.x * blockDim.x) {
    float4 v = ((const float4*)x)[idx];
    ushort4 h, l;
    h.x = f2bs(v.x); l.x = f2bs(v.x - bs2f(h.x));
    h.y = f2bs(v.y); l.y = f2bs(v.y - bs2f(h.y));
    h.z = f2bs(v.z); l.z = f2bs(v.z - bs2f(h.z));
    h.w = f2bs(v.w); l.w = f2bs(v.w - bs2f(h.w));
    ((ushort4*)hiA)[idx] = h;
    ((ushort4*)loA)[idx] = l;
  }
}

// ---------------------------------------------------------------------------
// convW: W[dir][256][384] fp32 -> W^T hi/lo bf16 [768 ncol][256 k].
// ---------------------------------------------------------------------------
__global__ __launch_bounds__(256) void convW_kernel(
    const float* __restrict__ W, ushort* __restrict__ WhiT,
    ushort* __restrict__ WloT) {
  const int ncol = blockIdx.x;           // 0..767
  const int dir = ncol / G_, j = ncol % G_;
  const int k = threadIdx.x;             // 0..255
  const float f = W[((size_t)dir * K_ + k) * G_ + j];
  const unsigned short hi = f2bs(f);
  WhiT[(size_t)ncol * K_ + k] = hi;
  WloT[(size_t)ncol * K_ + k] = f2bs(f - bs2f(hi));
}

// ---------------------------------------------------------------------------
// gemm3: C[M,768] = A[M,256] @ W^T' + bias, bf16 hi/lo 3-term split MFMA.
// ---------------------------------------------------------------------------
template <typename XT>
__global__ __launch_bounds__(256, 2) void gemm3_kernel(
    const ushort* __restrict__ Ahi, const ushort* __restrict__ Alo,
    const ushort* __restrict__ WhiT, const ushort* __restrict__ WloT,
    const float* __restrict__ bbias, XT* __restrict__ xp) {
  const int m0 = blockIdx.x * 128;
  const int n0 = blockIdx.y * 128;
  const int tid = threadIdx.x;
  const int w = tid >> 6, lane = tid & 63;
  const int wm = w >> 1, wn = w & 1;
  const int col = lane & 15, quad = lane >> 4;

  __shared__ __align__(16) ushort AH[128 * LDSROW];
  __shared__ __align__(16) ushort AL[128 * LDSROW];
  __shared__ __align__(16) ushort BH[128 * LDSROW];
  __shared__ __align__(16) ushort BL[128 * LDSROW];

  f32x4 acc[4][4];
#pragma unroll
  for (int i = 0; i < 4; ++i)
#pragma unroll
    for (int n = 0; n < 4; ++n) acc[i][n] = (f32x4){0.f, 0.f, 0.f, 0.f};

  const ushort* gsrc = (w == 0) ? Ahi : (w == 1) ? Alo : (w == 2) ? WhiT : WloT;
  ushort* lds = (w == 0) ? AH : (w == 1) ? AL : (w == 2) ? BH : BL;
  const int rbase = (w < 2) ? m0 : n0;

  for (int kb = 0; kb < K_; kb += 64) {
#pragma unroll
    for (int q = 0; q < 16; ++q) {
      const int slot = q * 64 + lane;
      const int r = slot >> 3, s = slot & 7;
      bf16x8 v = *(const bf16x8*)(gsrc + (size_t)(rbase + r) * K_ + kb + s * 8);
      *(bf16x8*)&lds[r * LDSROW + s * 8] = v;
    }
    __syncthreads();
#pragma unroll
    for (int z = 0; z < 2; ++z) {
      const int cc8 = (z * 4 + quad) * 8;
      bf16x8 ah[4], al[4], bh[4], bl[4];
#pragma unroll
      for (int i = 0; i < 4; ++i) {
        const int row = wm * 64 + i * 16 + col;
        ah[i] = *(const bf16x8*)&AH[row * LDSROW + cc8];
        al[i] = *(const bf16x8*)&AL[row * LDSROW + cc8];
      }
#pragma unroll
      for (int n = 0; n < 4; ++n) {
        const int row = wn * 64 + n * 16 + col;
        bh[n] = *(const bf16x8*)&BH[row * LDSROW + cc8];
        bl[n] = *(const bf16x8*)&BL[row * LDSROW + cc8];
      }
#pragma unroll
      for (int i = 0; i < 4; ++i)
#pragma unroll
        for (int n = 0; n < 4; ++n) {
          acc[i][n] = mfma16(ah[i], bh[n], acc[i][n]);
          acc[i][n] = mfma16(al[i], bh[n], acc[i][n]);
          acc[i][n] = mfma16(ah[i], bl[n], acc[i][n]);
        }
    }
    __syncthreads();
  }

  const int dir = (n0 >= G_) ? 1 : 0;
#pragma unroll
  for (int n = 0; n < 4; ++n) {
    const int ncol = n0 + wn * 64 + n * 16 + col;
    const int g = ncol - dir * G_;
    const float bv = bbias[dir * 2 * G_ + g];
#pragma unroll
    for (int i = 0; i < 4; ++i) {
      const int mb = m0 + wm * 64 + i * 16 + quad * 4;
#pragma unroll
      for (int r = 0; r < 4; ++r) {
        const int m = mb + r;
        const int bb = m >> 9;          // T_ = 512
        const int t = m & (T_ - 1);
        stor(xp + ((size_t)(dir * T_ + t) * B_ + bb) * G_ + g,
             acc[i][n][r] + bv);
      }
    }
  }
}

DEV float4 ldU4(const float* U, int col, int k0) {
  float4 v;
  v.x = U[(size_t)(k0 + 0) * G_ + col];
  v.y = U[(size_t)(k0 + 1) * G_ + col];
  v.z = U[(size_t)(k0 + 2) * G_ + col];
  v.w = U[(size_t)(k0 + 3) * G_ + col];
  return v;
}

// ---------------------------------------------------------------------------
// Recurrence. Grid (128, 2): 2 batch rows/block, 768 threads.
// R5 was LDS-return-BW-bound (12 waves x 32 ds_read_b128 x 1024B = 3072 cy/step
// = measured). Fix: thread (cg=tid>>3, kc=tid&7) computes 4 columns
// [4cg,4cg+4) over k-chunk {32i+4kc..+4 : i<4} -> 8 ds_read_b128/thread (4x
// less LDS), 64 v_pk_fma_f32, DPP-butterfly 8-lane k-reduction (VALU pipe,
// not ds_swizzle). U: 64 floats in 16 named float4s, pinned;
// waves_per_eu(3,3) removes the compiler's incentive to dump U for occupancy.
// ---------------------------------------------------------------------------
template <typename XT, bool LAST>
__global__ __attribute__((amdgpu_flat_work_group_size(768, 768),
                          amdgpu_waves_per_eu(3, 3))) void rec_kernel(
    const XT* __restrict__ xp, const float* __restrict__ Ubase,
    const float* __restrict__ bbase, ushort* __restrict__ seqH,
    ushort* __restrict__ seqL, float* __restrict__ fin) {
  const int dir = blockIdx.y;
  const float* U = Ubase + dir * (H_ * G_);
  const float* bh = bbase + dir * (2 * G_) + G_;
  const int b0 = blockIdx.x * 2;
  const int tid = threadIdx.x;
  const int kc = tid & 7;        // k-chunk selector (lane bits 0-2)
  const int cg = tid >> 3;       // column group 0..95
  const int kc4 = kc * 4;

  __shared__ __align__(16) float hbuf[2][H_];
  __shared__ float rec_s[2][G_];

  // U fragments: u{c}{i} covers col cg*4+c, k in [i*32+kc*4, +4)
#define LDU(c, i) ldU4(U, cg * 4 + (c), (i) * 32 + kc4)
  float4 u00 = LDU(0, 0), u01 = LDU(0, 1), u02 = LDU(0, 2), u03 = LDU(0, 3);
  float4 u10 = LDU(1, 0), u11 = LDU(1, 1), u12 = LDU(1, 2), u13 = LDU(1, 3);
  float4 u20 = LDU(2, 0), u21 = LDU(2, 1), u22 = LDU(2, 2), u23 = LDU(2, 3);
  float4 u30 = LDU(3, 0), u31 = LDU(3, 1), u32 = LDU(3, 2), u33 = LDU(3, 3);
#undef LDU
  pin4(u00); pin4(u01); pin4(u02); pin4(u03);
  pin4(u10); pin4(u11); pin4(u12); pin4(u13);
  pin4(u20); pin4(u21); pin4(u22); pin4(u23);
  pin4(u30); pin4(u31); pin4(u32); pin4(u33);

  const int wc = kc & 3, wr = kc >> 2;     // this thread's rec_s write slot
  const float bmine = bh[cg * 4 + wc];

  const int grow = tid >> 7;        // gate-phase row (tid < 256)
  const int gu = tid & (H_ - 1);    // gate-phase unit
  const bool gateT = tid < 2 * H_;

  if (gateT) hbuf[grow][gu] = 0.f;

  const XT* xbase = xp + (size_t)(dir * T_) * B_ * G_;

  XT xzc{}, xrc{}, xhc{};
  {
    const int t0 = dir ? (T_ - 1) : 0;
    if (gateT) {
      const XT* xr_ = xbase + ((size_t)t0 * B_ + b0 + grow) * G_ + gu;
      xzc = xr_[0];
      xrc = xr_[H_];
      xhc = xr_[2 * H_];
    }
  }
  barrier_lds();

  for (int it = 0; it < T_; ++it) {
    const int t = dir ? (T_ - 1 - it) : it;

    // --- prefetch xp for step it+1 (hidden under the dot phase) ---
    XT xzn = xzc, xrn = xrc, xhn = xhc;
    if (gateT && (it + 1 < T_)) {
      const int tn = dir ? (t - 1) : (t + 1);
      const XT* xr_ = xbase + ((size_t)tn * B_ + b0 + grow) * G_ + gu;
      xzn = xr_[0];
      xrn = xr_[H_];
      xhn = xr_[2 * H_];
    }

    // --- dot phase: packed-fp32 FMA, 4 cols x 2 rows per thread ---
    f32x2 a00 = {0.f, 0.f}, a01 = {0.f, 0.f}, a02 = {0.f, 0.f}, a03 = {0.f, 0.f};
    f32x2 a10 = {0.f, 0.f}, a11 = {0.f, 0.f}, a12 = {0.f, 0.f}, a13 = {0.f, 0.f};
#define FMA2(acc, h4, u4)                                              \
  {                                                                    \
    const f32x2* hp_ = (const f32x2*)&(h4);                            \
    const f32x2* up_ = (const f32x2*)&(u4);                            \
    acc = __builtin_elementwise_fma(hp_[0], up_[0], acc);              \
    acc = __builtin_elementwise_fma(hp_[1], up_[1], acc);              \
  }
#define DOT_I(i, uA, uB, uC, uD)                                       \
  {                                                                    \
    float4 h0 = *(const float4*)&hbuf[0][(i) * 32 + kc4];              \
    float4 h1 = *(const float4*)&hbuf[1][(i) * 32 + kc4];              \
    FMA2(a00, h0, uA) FMA2(a01, h0, uB) FMA2(a02, h0, uC)              \
    FMA2(a03, h0, uD)                                                  \
    FMA2(a10, h1, uA) FMA2(a11, h1, uB) FMA2(a12, h1, uC)              \
    FMA2(a13, h1, uD)                                                  \
  }
    DOT_I(0, u00, u10, u20, u30)
    DOT_I(1, u01, u11, u21, u31)
    DOT_I(2, u02, u12, u22, u32)
    DOT_I(3, u03, u13, u23, u33)
#undef DOT_I
#undef FMA2

    float s00 = a00.x + a00.y, s01 = a01.x + a01.y;
    float s02 = a02.x + a02.y, s03 = a03.x + a03.y;
    float s10 = a10.x + a10.y, s11 = a11.x + a11.y;
    float s12 = a12.x + a12.y, s13 = a13.x + a13.y;
    s00 = dpp_red8(s00); s01 = dpp_red8(s01);
    s02 = dpp_red8(s02); s03 = dpp_red8(s03);
    s10 = dpp_red8(s10); s11 = dpp_red8(s11);
    s12 = dpp_red8(s12); s13 = dpp_red8(s13);

    const float va = wc == 0 ? s00 : wc == 1 ? s01 : wc == 2 ? s02 : s03;
    const float vb = wc == 0 ? s10 : wc == 1 ? s11 : wc == 2 ? s12 : s13;
    rec_s[wr][cg * 4 + wc] = (wr ? vb : va) + bmine;
    barrier_lds();

    // --- gate phase (first 256 threads) ---
    if (gateT) {
      const float xz = tof(xzc);
      const float xr = tof(xrc);
      const float xh = tof(xhc);
      const float rz = rec_s[grow][gu];
      const float rr = rec_s[grow][H_ + gu];
      const float rh = rec_s[grow][2 * H_ + gu];
      const float z = fsigmoid(xz + rz);
      const float r = fsigmoid(xr + rr);
      const float hh = ftanh(xh + r * rh);
      const float hold = hbuf[grow][gu];
      const float hn = z * hold + (1.f - z) * hh;
      hbuf[grow][gu] = hn;
      if constexpr (!LAST) {
        const size_t sidx =
            ((size_t)(b0 + grow) * T_ + t) * (2 * H_) + dir * H_ + gu;
        const unsigned short hi = f2bs(hn);
        seqH[sidx] = hi;
        seqL[sidx] = f2bs(hn - bs2f(hi));
      }
      xzc = xzn;
      xrc = xrn;
      xhc = xhn;
    }
    barrier_lds();
  }

  if constexpr (LAST) {
    if (gateT) fin[(size_t)(b0 + grow) * (2 * H_) + dir * H_ + gu] =
        hbuf[grow][gu];
  }
}

// ---------------------------------------------------------------------------
// Dense head: out[b] = sigmoid(fin[b][:] . Wd + bd)
// ---------------------------------------------------------------------------
__global__ void dense_kernel(const float* __restrict__ fin,
                             const float* __restrict__ Wd,
                             const float* __restrict__ bd,
                             float* __restrict__ out) {
  __shared__ float w[2 * H_];
  const int tid = threadIdx.x;
  w[tid] = Wd[tid];
  __syncthreads();
  float s = bd[0];
  const float* row = fin + tid * (2 * H_);
#pragma unroll 8
  for (int jj = 0; jj < 2 * H_; ++jj) s = fmaf(row[jj], w[jj], s);
  out[tid] = 1.f / (1.f + __expf(-s));
}

// ---------------------------------------------------------------------------
template <typename XT>
static void run_model(const float* x, const float* Ws, const float* Us,
                      const float* bs, const float* Wd, const float* bd,
                      float* out, char* ws, hipStream_t stream) {
  const size_t xpB = (size_t)2 * T_ * B_ * G_ * sizeof(XT);
  const size_t seqB = (size_t)B_ * T_ * 2 * H_ * 2;  // bf16 bits
  XT* xp = (XT*)ws;
  ushort* sHA = (ushort*)(ws + xpB);
  ushort* sLA = (ushort*)(ws + xpB + seqB);
  ushort* sHB = (ushort*)(ws + xpB + 2 * seqB);
  ushort* sLB = (ushort*)(ws + xpB + 3 * seqB);
  ushort* WhiT = (ushort*)(ws + xpB + 4 * seqB);
  ushort* WloT = WhiT + (size_t)768 * K_;
  float* fin = (float*)(ws + xpB + 4 * seqB + (size_t)2 * 768 * K_ * 2);

  convX_kernel<<<4096, 256, 0, stream>>>(x, sHB, sLB);

  const ushort* AHs[3] = {sHB, sHA, sHB};
  const ushort* ALs[3] = {sLB, sLA, sLB};
  ushort* oH[3] = {sHA, sHB, nullptr};
  ushort* oL[3] = {sLA, sLB, nullptr};

  for (int l = 0; l < 3; ++l) {
    const float* Wl = Ws + (size_t)l * 2 * K_ * G_;
    const float* bl = bs + (size_t)l * 4 * G_;
    const float* Ul = Us + (size_t)l * 2 * H_ * G_;
    convW_kernel<<<768, 256, 0, stream>>>(Wl, WhiT, WloT);
    gemm3_kernel<XT><<<dim3(M_ / 128, 6), 256, 0, stream>>>(
        AHs[l], ALs[l], WhiT, WloT, bl, xp);
    if (l < 2)
      rec_kernel<XT, false><<<dim3(B_ / 2, 2), 768, 0, stream>>>(
          xp, Ul, bl, oH[l], oL[l], nullptr);
    else
      rec_kernel<XT, true><<<dim3(B_ / 2, 2), 768, 0, stream>>>(
          xp, Ul, bl, nullptr, nullptr, fin);
  }
  dense_kernel<<<1, B_, 0, stream>>>(fin, Wd, bd, out);
}

extern "C" void kernel_launch(void* const* d_in, const int* in_sizes, int n_in,
                              void* d_out, int out_size, void* d_ws,
                              size_t ws_size, hipStream_t stream) {
  const float* x = (const float*)d_in[0];
  const float* Ws = (const float*)d_in[1];
  const float* Us = (const float*)d_in[2];
  const float* bs = (const float*)d_in[3];
  const float* Wd = (const float*)d_in[4];
  const float* bd = (const float*)d_in[5];
  float* out = (float*)d_out;
  char* ws = (char*)d_ws;

  const size_t seqB = (size_t)B_ * T_ * 2 * H_ * 2;
  const size_t wtB = (size_t)2 * 768 * K_ * 2;
  const size_t finB = (size_t)B_ * 2 * H_ * 4;
  const size_t xp32 = (size_t)2 * T_ * B_ * G_ * 4;
  const size_t tierA = xp32 + 4 * seqB + wtB + finB;      // ~641 MiB, fp32 xp
  if (ws_size >= tierA)
    run_model<float>(x, Ws, Us, bs, Wd, bd, out, ws, stream);
  else
    run_model<bf16>(x, Ws, Us, bs, Wd, bd, out, ws, stream);
}